// Round 1
// baseline (280.129 us; speedup 1.0000x reference)
//
#include <hip/hip_runtime.h>

#define N_NODES 100000
#define N_EDGES 800000
#define D 64

// deg[i] = 1.0 (self-loop contribution)
__global__ void k_init_deg(float* __restrict__ deg) {
    int i = blockIdx.x * 256 + threadIdx.x;
    if (i < N_NODES) deg[i] = 1.0f;
}

// deg[col[e]] += 1 for each real edge
__global__ void k_count_deg(const int* __restrict__ col, float* __restrict__ deg) {
    int e = blockIdx.x * 256 + threadIdx.x;
    if (e < N_EDGES) atomicAdd(&deg[col[e]], 1.0f);
}

// deg -> deg^{-1/2} in place (deg >= 1 always, but keep the guard to match ref)
__global__ void k_dinv(float* __restrict__ deg) {
    int i = blockIdx.x * 256 + threadIdx.x;
    if (i < N_NODES) {
        float d = deg[i];
        deg[i] = d > 0.0f ? rsqrtf(d) : 0.0f;
    }
}

// xw = x @ W; out = b + dinv^2 * xw (self-loop term); xws = dinv * xw
// block = 256 threads = 4 rows x 64 cols
__global__ void k_xw(const float* __restrict__ x, const float* __restrict__ W,
                     const float* __restrict__ b, const float* __restrict__ dinv,
                     float* __restrict__ out, float* __restrict__ xws) {
    __shared__ float Ws[D * D];   // 16 KB
    __shared__ float xs[4 * D];   // 1 KB

    int tid = threadIdx.x;
    for (int i = tid; i < D * D; i += 256) Ws[i] = W[i];

    int lr = tid >> 6;        // local row 0..3
    int c  = tid & 63;        // output column
    int r  = blockIdx.x * 4 + lr;
    if (r < N_NODES) xs[lr * D + c] = x[r * D + c];
    __syncthreads();

    if (r >= N_NODES) return;

    float acc = 0.0f;
#pragma unroll
    for (int k = 0; k < D; ++k)
        acc = fmaf(xs[lr * D + k], Ws[k * D + c], acc);

    float di = dinv[r];
    out[r * D + c] = b[c] + di * di * acc;  // bias + self-loop message
    xws[r * D + c] = di * acc;              // source-normalized features
}

// For each edge e, lane j: out[col[e]][j] += xws[row[e]][j] * dinv[col[e]]
__global__ void k_scatter(const int* __restrict__ row, const int* __restrict__ col,
                          const float* __restrict__ dinv, const float* __restrict__ xws,
                          float* __restrict__ out) {
    int gid = blockIdx.x * 256 + threadIdx.x;
    int e = gid >> 6;
    if (e >= N_EDGES) return;
    int j = gid & 63;
    int r = row[e];
    int c = col[e];
    float v = xws[r * D + j] * dinv[c];
    atomicAdd(&out[c * D + j], v);
}

extern "C" void kernel_launch(void* const* d_in, const int* in_sizes, int n_in,
                              void* d_out, int out_size, void* d_ws, size_t ws_size,
                              hipStream_t stream) {
    const float* x  = (const float*)d_in[0];
    const int*   ei = (const int*)d_in[1];     // [2, E] int32 (JAX x64 off)
    const float* W  = (const float*)d_in[2];
    const float* b  = (const float*)d_in[3];
    float* out = (float*)d_out;

    float* deg = (float*)d_ws;       // N floats (becomes dinv after k_dinv)
    float* xws = deg + N_NODES;      // N*D floats

    const int* row = ei;             // source nodes
    const int* col = ei + N_EDGES;   // target nodes

    k_init_deg <<<(N_NODES + 255) / 256, 256, 0, stream>>>(deg);
    k_count_deg<<<(N_EDGES + 255) / 256, 256, 0, stream>>>(col, deg);
    k_dinv     <<<(N_NODES + 255) / 256, 256, 0, stream>>>(deg);
    k_xw       <<<(N_NODES + 3) / 4,     256, 0, stream>>>(x, W, b, deg, out, xws);

    long long scatter_threads = (long long)N_EDGES * D;
    k_scatter  <<<(int)((scatter_threads + 255) / 256), 256, 0, stream>>>(row, col, deg, xws, out);
}

// Round 2
// 229.288 us; speedup vs baseline: 1.2217x; 1.2217x over previous
//
#include <hip/hip_runtime.h>

#define N_NODES 100000
#define N_EDGES 800000
#define D 64
#define SCAN_B 1024
#define NB ((N_NODES + SCAN_B - 1) / SCAN_B)   // 98

__device__ __forceinline__ int wave_incl_scan(int v) {
#pragma unroll
    for (int off = 1; off < 64; off <<= 1) {
        int n = __shfl_up(v, off, 64);
        if ((threadIdx.x & 63) >= off) v += n;
    }
    return v;
}

// cnt[col[e]] += 1 (int) for each real edge
__global__ void k_count(const int* __restrict__ col, int* __restrict__ cnt) {
    int e = blockIdx.x * 256 + threadIdx.x;
    if (e < N_EDGES) atomicAdd(&cnt[col[e]], 1);
}

// per-1024-block exclusive scan of cnt -> start (partial), block totals -> bsum
__global__ void k_scan1(const int* __restrict__ cnt, int* __restrict__ start,
                        int* __restrict__ bsum) {
    __shared__ int wsum[16];
    int tid = threadIdx.x;
    int gid = blockIdx.x * SCAN_B + tid;
    int v = (gid < N_NODES) ? cnt[gid] : 0;
    int incl = wave_incl_scan(v);
    int wid = tid >> 6, lane = tid & 63;
    if (lane == 63) wsum[wid] = incl;
    __syncthreads();
    if (wid == 0) {
        int wv = (lane < 16) ? wsum[lane] : 0;
        int wincl = wave_incl_scan(wv);
        if (lane < 16) wsum[lane] = wincl - wv;  // exclusive wave offsets
    }
    __syncthreads();
    int excl = incl - v + wsum[wid];
    if (gid < N_NODES) start[gid] = excl;
    if (tid == SCAN_B - 1) bsum[blockIdx.x] = excl + v;
}

// exclusive scan of the 98 block sums (single block, 128 threads)
__global__ void k_scan2(int* __restrict__ bsum) {
    __shared__ int wsum[2];
    int tid = threadIdx.x;
    int v = (tid < NB) ? bsum[tid] : 0;
    int incl = wave_incl_scan(v);
    int wid = tid >> 6, lane = tid & 63;
    if (lane == 63) wsum[wid] = incl;
    __syncthreads();
    int off = (wid == 1) ? wsum[0] : 0;
    if (tid < NB) bsum[tid] = incl - v + off;
}

// add block offsets; copy to cursor; start[N]=E
__global__ void k_scan3(int* __restrict__ start, int* __restrict__ cursor,
                        const int* __restrict__ bsum) {
    int gid = blockIdx.x * SCAN_B + threadIdx.x;
    if (gid < N_NODES) {
        int s = start[gid] + bsum[gid >> 10];
        start[gid] = s;
        cursor[gid] = s;
    }
    if (gid == 0) start[N_NODES] = N_EDGES;
}

// dinv[i] = rsqrt(cnt[i] + 1)  (self-loop included; always > 0)
__global__ void k_dinv(const int* __restrict__ cnt, float* __restrict__ dinv) {
    int i = blockIdx.x * 256 + threadIdx.x;
    if (i < N_NODES) dinv[i] = rsqrtf((float)(cnt[i] + 1));
}

// bucket edges by target: srow[cursor[col[e]]++] = row[e]
__global__ void k_bucket(const int* __restrict__ row, const int* __restrict__ col,
                         int* __restrict__ cursor, int* __restrict__ srow) {
    int e = blockIdx.x * 256 + threadIdx.x;
    if (e < N_EDGES) {
        int p = atomicAdd(&cursor[col[e]], 1);
        srow[p] = row[e];
    }
}

// xws = dinv * (x @ W). 32 rows/block, 256 threads (4 row-groups x 64 cols).
#define XW_ROWS 32
__global__ void k_xw(const float* __restrict__ x, const float* __restrict__ W,
                     const float* __restrict__ dinv, float* __restrict__ xws) {
    __shared__ float Ws[D * D];          // 16 KB
    __shared__ float xs[XW_ROWS][D];     // 8 KB
    int tid = threadIdx.x;
    for (int i = tid; i < D * D; i += 256) Ws[i] = W[i];
    int base = blockIdx.x * XW_ROWS;
    for (int i = tid; i < XW_ROWS * D; i += 256) {
        int rr = i >> 6, r = base + rr;
        xs[rr][i & 63] = (r < N_NODES) ? x[r * D + (i & 63)] : 0.0f;
    }
    __syncthreads();
    int c = tid & 63;
    int rg = tid >> 6;
    for (int rr = rg; rr < XW_ROWS; rr += 4) {
        int r = base + rr;
        if (r >= N_NODES) break;
        float acc = 0.0f;
#pragma unroll
        for (int k = 0; k < D; ++k)
            acc = fmaf(xs[rr][k], Ws[k * D + c], acc);  // xs: wave-broadcast, Ws: 2-way (free)
        xws[r * D + c] = dinv[r] * acc;
    }
}

// One wave per node c: out[c][j] = b[j] + dinv[c] * (xws[c][j] + sum_e xws[srow[e]][j])
__global__ void k_gather(const int* __restrict__ start, const int* __restrict__ srow,
                         const float* __restrict__ dinv, const float* __restrict__ b,
                         const float* __restrict__ xws, float* __restrict__ out) {
    int gid = blockIdx.x * 256 + threadIdx.x;
    int c = gid >> 6;
    if (c >= N_NODES) return;
    int j = gid & 63;
    int s = start[c], e = start[c + 1];
    float acc = xws[c * D + j];          // self-loop message (dinv[c]*xw[c])
    for (int i = s; i < e; ++i) {
        int r = srow[i];                 // wave-uniform address
        acc += xws[r * D + j];
    }
    out[c * D + j] = b[j] + dinv[c] * acc;
}

// ---- fallback (round-1 atomic path) if ws_size is too small for CSR ----
__global__ void k_init_deg_f(float* __restrict__ deg) {
    int i = blockIdx.x * 256 + threadIdx.x;
    if (i < N_NODES) deg[i] = 1.0f;
}
__global__ void k_count_f(const int* __restrict__ col, float* __restrict__ deg) {
    int e = blockIdx.x * 256 + threadIdx.x;
    if (e < N_EDGES) atomicAdd(&deg[col[e]], 1.0f);
}
__global__ void k_dinv_f(float* __restrict__ deg) {
    int i = blockIdx.x * 256 + threadIdx.x;
    if (i < N_NODES) deg[i] = rsqrtf(deg[i]);
}
__global__ void k_self(const float* __restrict__ dinv, const float* __restrict__ b,
                       const float* __restrict__ xws, float* __restrict__ out) {
    int i = blockIdx.x * 256 + threadIdx.x;
    if (i < N_NODES * D) out[i] = b[i & 63] + dinv[i >> 6] * xws[i];
}
__global__ void k_scatter_f(const int* __restrict__ row, const int* __restrict__ col,
                            const float* __restrict__ dinv, const float* __restrict__ xws,
                            float* __restrict__ out) {
    int gid = blockIdx.x * 256 + threadIdx.x;
    int e = gid >> 6;
    if (e >= N_EDGES) return;
    int j = gid & 63;
    float v = xws[row[e] * D + j] * dinv[col[e]];
    atomicAdd(&out[col[e] * D + j], v);
}

extern "C" void kernel_launch(void* const* d_in, const int* in_sizes, int n_in,
                              void* d_out, int out_size, void* d_ws, size_t ws_size,
                              hipStream_t stream) {
    const float* x  = (const float*)d_in[0];
    const int*   ei = (const int*)d_in[1];     // [2, E] int32
    const float* W  = (const float*)d_in[2];
    const float* b  = (const float*)d_in[3];
    float* out = (float*)d_out;

    const int* row = ei;
    const int* col = ei + N_EDGES;

    // workspace layout
    char* ws = (char*)d_ws;
    int*   cnt    = (int*)ws;                       ws += (size_t)N_NODES * 4;
    float* dinv   = (float*)ws;                     ws += (size_t)N_NODES * 4;
    int*   start  = (int*)ws;                       ws += (size_t)(N_NODES + 1) * 4;
    int*   cursor = (int*)ws;                       ws += (size_t)N_NODES * 4;
    int*   bsum   = (int*)ws;                       ws += (size_t)((NB + 1) & ~1) * 4;
    int*   srow   = (int*)ws;                       ws += (size_t)N_EDGES * 4;
    float* xws    = (float*)ws;                     ws += (size_t)N_NODES * D * 4;
    size_t needed = (size_t)(ws - (char*)d_ws);

    if (ws_size >= needed) {
        hipMemsetAsync(cnt, 0, (size_t)N_NODES * 4, stream);
        k_count <<<(N_EDGES + 255) / 256, 256, 0, stream>>>(col, cnt);
        k_scan1 <<<NB, SCAN_B, 0, stream>>>(cnt, start, bsum);
        k_scan2 <<<1, 128, 0, stream>>>(bsum);
        k_scan3 <<<NB, SCAN_B, 0, stream>>>(start, cursor, bsum);
        k_dinv  <<<(N_NODES + 255) / 256, 256, 0, stream>>>(cnt, dinv);
        k_xw    <<<(N_NODES + XW_ROWS - 1) / XW_ROWS, 256, 0, stream>>>(x, W, dinv, xws);
        k_bucket<<<(N_EDGES + 255) / 256, 256, 0, stream>>>(row, col, cursor, srow);
        long long gt = (long long)N_NODES * D;
        k_gather<<<(int)((gt + 255) / 256), 256, 0, stream>>>(start, srow, dinv, b, xws, out);
    } else {
        // fallback: atomic scatter (round-1 structure)
        float* degf = (float*)d_ws;
        float* xws2 = degf + N_NODES;
        k_init_deg_f<<<(N_NODES + 255) / 256, 256, 0, stream>>>(degf);
        k_count_f   <<<(N_EDGES + 255) / 256, 256, 0, stream>>>(col, degf);
        k_dinv_f    <<<(N_NODES + 255) / 256, 256, 0, stream>>>(degf);
        k_xw        <<<(N_NODES + XW_ROWS - 1) / XW_ROWS, 256, 0, stream>>>(x, W, degf, xws2);
        long long st = (long long)N_NODES * D;
        k_self      <<<(int)((st + 255) / 256), 256, 0, stream>>>(degf, b, xws2, out);
        long long et = (long long)N_EDGES * D;
        k_scatter_f <<<(int)((et + 255) / 256), 256, 0, stream>>>(row, col, degf, xws2, out);
    }
}

// Round 3
// 185.277 us; speedup vs baseline: 1.5119x; 1.2375x over previous
//
#include <hip/hip_runtime.h>

#define N_NODES 100000
#define N_EDGES 800000
#define D 64
#define SCAN_B 1024
#define NB ((N_NODES + SCAN_B - 1) / SCAN_B)   // 98

__device__ __forceinline__ int wave_incl_scan(int v) {
#pragma unroll
    for (int off = 1; off < 64; off <<= 1) {
        int n = __shfl_up(v, off, 64);
        if ((threadIdx.x & 63) >= off) v += n;
    }
    return v;
}

// cnt[col[e]] += 1 (int) for each real edge
__global__ void k_count(const int* __restrict__ col, int* __restrict__ cnt) {
    int e = blockIdx.x * 256 + threadIdx.x;
    if (e < N_EDGES) atomicAdd(&cnt[col[e]], 1);
}

// per-1024-block exclusive scan of cnt -> start (partial), block totals -> bsum
__global__ void k_scan1(const int* __restrict__ cnt, int* __restrict__ start,
                        int* __restrict__ bsum) {
    __shared__ int wsum[16];
    int tid = threadIdx.x;
    int gid = blockIdx.x * SCAN_B + tid;
    int v = (gid < N_NODES) ? cnt[gid] : 0;
    int incl = wave_incl_scan(v);
    int wid = tid >> 6, lane = tid & 63;
    if (lane == 63) wsum[wid] = incl;
    __syncthreads();
    if (wid == 0) {
        int wv = (lane < 16) ? wsum[lane] : 0;
        int wincl = wave_incl_scan(wv);
        if (lane < 16) wsum[lane] = wincl - wv;  // exclusive wave offsets
    }
    __syncthreads();
    int excl = incl - v + wsum[wid];
    if (gid < N_NODES) start[gid] = excl;
    if (tid == SCAN_B - 1) bsum[blockIdx.x] = excl + v;
}

// exclusive scan of the 98 block sums (single block, 128 threads)
__global__ void k_scan2(int* __restrict__ bsum) {
    __shared__ int wsum[2];
    int tid = threadIdx.x;
    int v = (tid < NB) ? bsum[tid] : 0;
    int incl = wave_incl_scan(v);
    int wid = tid >> 6, lane = tid & 63;
    if (lane == 63) wsum[wid] = incl;
    __syncthreads();
    int off = (wid == 1) ? wsum[0] : 0;
    if (tid < NB) bsum[tid] = incl - v + off;
}

// add block offsets; copy to cursor; dinv = rsqrt(cnt+1); start[N]=E
__global__ void k_scan3(int* __restrict__ start, int* __restrict__ cursor,
                        const int* __restrict__ bsum, const int* __restrict__ cnt,
                        float* __restrict__ dinv) {
    int gid = blockIdx.x * SCAN_B + threadIdx.x;
    if (gid < N_NODES) {
        int s = start[gid] + bsum[gid >> 10];
        start[gid] = s;
        cursor[gid] = s;
        dinv[gid] = rsqrtf((float)(cnt[gid] + 1));   // +1 = self-loop
    }
    if (gid == 0) start[N_NODES] = N_EDGES;
}

// bucket edges by target: srow[cursor[col[e]]++] = row[e]
__global__ void k_bucket(const int* __restrict__ row, const int* __restrict__ col,
                         int* __restrict__ cursor, int* __restrict__ srow) {
    int e = blockIdx.x * 256 + threadIdx.x;
    if (e < N_EDGES) {
        int p = atomicAdd(&cursor[col[e]], 1);
        srow[p] = row[e];
    }
}

// xws = dinv * (x @ W). 64 rows/block, 256 threads = 16x16, 4x4 register tile.
// All k-loop LDS traffic is ds_read_b128: 2 b128 per 16 FMA.
#define XW_ROWS 64
#define XSTRIDE (D + 4)   // pad keeps 16B alignment (68 % 4 == 0), breaks bank stride
__global__ __launch_bounds__(256) void k_xw(const float4* __restrict__ x4,
                                            const float4* __restrict__ W4,
                                            const float* __restrict__ dinv,
                                            float4* __restrict__ xws4) {
    __shared__ float Ws[D * D];              // 16 KB
    __shared__ float xs[XW_ROWS][XSTRIDE];   // 17 KB

    int tid = threadIdx.x;
    int base = blockIdx.x * XW_ROWS;

    for (int i = tid; i < D * D / 4; i += 256)
        ((float4*)Ws)[i] = W4[i];
    for (int i = tid; i < XW_ROWS * 16; i += 256) {
        int r = i >> 4, k4 = i & 15;
        int gr = base + r;
        float4 v = (gr < N_NODES) ? x4[(size_t)gr * 16 + k4] : float4{0, 0, 0, 0};
        *(float4*)&xs[r][k4 * 4] = v;
    }
    __syncthreads();

    int tx = tid & 15, ty = tid >> 4;
    int r0 = ty * 4, c0 = tx * 4;

    float4 acc[4] = {{0,0,0,0},{0,0,0,0},{0,0,0,0},{0,0,0,0}};
#pragma unroll
    for (int kq = 0; kq < 16; ++kq) {
        float xr[4][4];
#pragma unroll
        for (int i = 0; i < 4; ++i)
            *(float4*)&xr[i][0] = *(const float4*)&xs[r0 + i][kq * 4];  // broadcast among 16 lanes
#pragma unroll
        for (int q = 0; q < 4; ++q) {
            float4 wv = *(const float4*)&Ws[(kq * 4 + q) * D + c0];     // 2-way aliasing: free
#pragma unroll
            for (int i = 0; i < 4; ++i) {
                acc[i].x = fmaf(xr[i][q], wv.x, acc[i].x);
                acc[i].y = fmaf(xr[i][q], wv.y, acc[i].y);
                acc[i].z = fmaf(xr[i][q], wv.z, acc[i].z);
                acc[i].w = fmaf(xr[i][q], wv.w, acc[i].w);
            }
        }
    }

#pragma unroll
    for (int i = 0; i < 4; ++i) {
        int gr = base + r0 + i;
        if (gr < N_NODES) {
            float di = dinv[gr];
            float4 o = {acc[i].x * di, acc[i].y * di, acc[i].z * di, acc[i].w * di};
            xws4[(size_t)gr * 16 + tx] = o;
        }
    }
}

// One wave per node c, 4 edges in flight (eslot = lane>>4), float4 per lane.
// out[c][:] = b + dinv[c] * (xws[c][:] + sum_e xws[srow[e]][:])
__global__ __launch_bounds__(256) void k_gather(const int* __restrict__ start,
                                                const int* __restrict__ srow,
                                                const float* __restrict__ dinv,
                                                const float4* __restrict__ b4,
                                                const float4* __restrict__ xws4,
                                                float4* __restrict__ out4) {
    int gid = blockIdx.x * 256 + threadIdx.x;
    int c = gid >> 6;
    if (c >= N_NODES) return;
    int lane = threadIdx.x & 63;
    int eslot = lane >> 4;     // which of 4 concurrent edges
    int cg = lane & 15;        // column group (4 floats)

    int s = start[c], e = start[c + 1];
    float4 acc = {0, 0, 0, 0};
    if (eslot == 0) acc = xws4[c * 16 + cg];   // self-loop message (dinv[c]*xw[c])

    for (int base = s; base < e; base += 4) {
        int i = base + eslot;
        if (i < e) {
            int r = srow[i];                    // 16-lane broadcast read
            float4 v = xws4[r * 16 + cg];       // 4 independent 256B rows in flight
            acc.x += v.x; acc.y += v.y; acc.z += v.z; acc.w += v.w;
        }
    }
    // reduce the 4 edge slots (lanes l, l^16, l^32, l^48)
    acc.x += __shfl_xor(acc.x, 16, 64);
    acc.y += __shfl_xor(acc.y, 16, 64);
    acc.z += __shfl_xor(acc.z, 16, 64);
    acc.w += __shfl_xor(acc.w, 16, 64);
    acc.x += __shfl_xor(acc.x, 32, 64);
    acc.y += __shfl_xor(acc.y, 32, 64);
    acc.z += __shfl_xor(acc.z, 32, 64);
    acc.w += __shfl_xor(acc.w, 32, 64);

    if (eslot == 0) {
        float di = dinv[c];
        float4 bb = b4[cg];
        float4 o = {bb.x + di * acc.x, bb.y + di * acc.y,
                    bb.z + di * acc.z, bb.w + di * acc.w};
        out4[c * 16 + cg] = o;
    }
}

extern "C" void kernel_launch(void* const* d_in, const int* in_sizes, int n_in,
                              void* d_out, int out_size, void* d_ws, size_t ws_size,
                              hipStream_t stream) {
    const float* x  = (const float*)d_in[0];
    const int*   ei = (const int*)d_in[1];     // [2, E] int32
    const float* W  = (const float*)d_in[2];
    const float* b  = (const float*)d_in[3];

    const int* row = ei;
    const int* col = ei + N_EDGES;

    // workspace layout, every region 256B-aligned (float4 access to xws)
    char* ws = (char*)d_ws;
    size_t off = 0;
    auto alloc = [&](size_t bytes) {
        char* p = ws + off;
        off = (off + bytes + 255) & ~(size_t)255;
        return p;
    };
    int*   cnt    = (int*)  alloc((size_t)N_NODES * 4);
    float* dinv   = (float*)alloc((size_t)N_NODES * 4);
    int*   start  = (int*)  alloc((size_t)(N_NODES + 1) * 4);
    int*   cursor = (int*)  alloc((size_t)N_NODES * 4);
    int*   bsum   = (int*)  alloc((size_t)NB * 4);
    int*   srow   = (int*)  alloc((size_t)N_EDGES * 4);
    float* xws    = (float*)alloc((size_t)N_NODES * D * 4);
    (void)ws_size;

    hipMemsetAsync(cnt, 0, (size_t)N_NODES * 4, stream);
    k_count <<<(N_EDGES + 255) / 256, 256, 0, stream>>>(col, cnt);
    k_scan1 <<<NB, SCAN_B, 0, stream>>>(cnt, start, bsum);
    k_scan2 <<<1, 128, 0, stream>>>(bsum);
    k_scan3 <<<NB, SCAN_B, 0, stream>>>(start, cursor, bsum, cnt, dinv);
    k_xw    <<<(N_NODES + XW_ROWS - 1) / XW_ROWS, 256, 0, stream>>>(
                (const float4*)x, (const float4*)W, dinv, (float4*)xws);
    k_bucket<<<(N_EDGES + 255) / 256, 256, 0, stream>>>(row, col, cursor, srow);

    long long gt = (long long)N_NODES * D;
    k_gather<<<(int)((gt + 255) / 256), 256, 0, stream>>>(
                start, srow, dinv, (const float4*)b, (const float4*)xws, (float4*)d_out);
}

// Round 4
// 181.086 us; speedup vs baseline: 1.5469x; 1.0231x over previous
//
#include <hip/hip_runtime.h>

#define N_NODES 100000
#define N_EDGES 800000
#define D 64
#define SCAN_B 1024
#define NB ((N_NODES + SCAN_B - 1) / SCAN_B)   // 98

__device__ __forceinline__ int wave_incl_scan(int v) {
#pragma unroll
    for (int off = 1; off < 64; off <<= 1) {
        int n = __shfl_up(v, off, 64);
        if ((threadIdx.x & 63) >= off) v += n;
    }
    return v;
}

// cnt[col[e]] += 1 (int) for each real edge
__global__ void k_count(const int* __restrict__ col, int* __restrict__ cnt) {
    int e = blockIdx.x * 256 + threadIdx.x;
    if (e < N_EDGES) atomicAdd(&cnt[col[e]], 1);
}

// per-1024-block exclusive scan of cnt -> start (partial), block totals -> bsum
__global__ void k_scan1(const int* __restrict__ cnt, int* __restrict__ start,
                        int* __restrict__ bsum) {
    __shared__ int wsum[16];
    int tid = threadIdx.x;
    int gid = blockIdx.x * SCAN_B + tid;
    int v = (gid < N_NODES) ? cnt[gid] : 0;
    int incl = wave_incl_scan(v);
    int wid = tid >> 6, lane = tid & 63;
    if (lane == 63) wsum[wid] = incl;
    __syncthreads();
    if (wid == 0) {
        int wv = (lane < 16) ? wsum[lane] : 0;
        int wincl = wave_incl_scan(wv);
        if (lane < 16) wsum[lane] = wincl - wv;  // exclusive wave offsets
    }
    __syncthreads();
    int excl = incl - v + wsum[wid];
    if (gid < N_NODES) start[gid] = excl;
    if (tid == SCAN_B - 1) bsum[blockIdx.x] = excl + v;
}

// exclusive scan of the 98 block sums (single block, 128 threads)
__global__ void k_scan2(int* __restrict__ bsum) {
    __shared__ int wsum[2];
    int tid = threadIdx.x;
    int v = (tid < NB) ? bsum[tid] : 0;
    int incl = wave_incl_scan(v);
    int wid = tid >> 6, lane = tid & 63;
    if (lane == 63) wsum[wid] = incl;
    __syncthreads();
    int off = (wid == 1) ? wsum[0] : 0;
    if (tid < NB) bsum[tid] = incl - v + off;
}

// add block offsets; copy to cursor; dinv = rsqrt(cnt+1); start[N]=E
__global__ void k_scan3(int* __restrict__ start, int* __restrict__ cursor,
                        const int* __restrict__ bsum, const int* __restrict__ cnt,
                        float* __restrict__ dinv) {
    int gid = blockIdx.x * SCAN_B + threadIdx.x;
    if (gid < N_NODES) {
        int s = start[gid] + bsum[gid >> 10];
        start[gid] = s;
        cursor[gid] = s;
        dinv[gid] = rsqrtf((float)(cnt[gid] + 1));   // +1 = self-loop
    }
    if (gid == 0) start[N_NODES] = N_EDGES;
}

// bucket edges by target: srow[cursor[col[e]]++] = row[e]
__global__ void k_bucket(const int* __restrict__ row, const int* __restrict__ col,
                         int* __restrict__ cursor, int* __restrict__ srow) {
    int e = blockIdx.x * 256 + threadIdx.x;
    if (e < N_EDGES) {
        int p = atomicAdd(&cursor[col[e]], 1);
        srow[p] = row[e];
    }
}

// xws = dinv * (x @ W). 64 rows/block, 256 threads = 16x16, 4x4 register tile.
// All k-loop LDS traffic is ds_read_b128: 2 b128 per 16 FMA.
#define XW_ROWS 64
#define XSTRIDE (D + 4)   // pad keeps 16B alignment (68 % 4 == 0), breaks bank stride
__global__ __launch_bounds__(256) void k_xw(const float4* __restrict__ x4,
                                            const float4* __restrict__ W4,
                                            const float* __restrict__ dinv,
                                            float4* __restrict__ xws4) {
    __shared__ float Ws[D * D];              // 16 KB
    __shared__ float xs[XW_ROWS][XSTRIDE];   // 17 KB

    int tid = threadIdx.x;
    int base = blockIdx.x * XW_ROWS;

    for (int i = tid; i < D * D / 4; i += 256)
        ((float4*)Ws)[i] = W4[i];
    for (int i = tid; i < XW_ROWS * 16; i += 256) {
        int r = i >> 4, k4 = i & 15;
        int gr = base + r;
        float4 v = (gr < N_NODES) ? x4[(size_t)gr * 16 + k4] : float4{0, 0, 0, 0};
        *(float4*)&xs[r][k4 * 4] = v;
    }
    __syncthreads();

    int tx = tid & 15, ty = tid >> 4;
    int r0 = ty * 4, c0 = tx * 4;

    float4 acc[4] = {{0,0,0,0},{0,0,0,0},{0,0,0,0},{0,0,0,0}};
#pragma unroll
    for (int kq = 0; kq < 16; ++kq) {
        float xr[4][4];
#pragma unroll
        for (int i = 0; i < 4; ++i)
            *(float4*)&xr[i][0] = *(const float4*)&xs[r0 + i][kq * 4];  // broadcast among 16 lanes
#pragma unroll
        for (int q = 0; q < 4; ++q) {
            float4 wv = *(const float4*)&Ws[(kq * 4 + q) * D + c0];     // 2-way aliasing: free
#pragma unroll
            for (int i = 0; i < 4; ++i) {
                acc[i].x = fmaf(xr[i][q], wv.x, acc[i].x);
                acc[i].y = fmaf(xr[i][q], wv.y, acc[i].y);
                acc[i].z = fmaf(xr[i][q], wv.z, acc[i].z);
                acc[i].w = fmaf(xr[i][q], wv.w, acc[i].w);
            }
        }
    }

#pragma unroll
    for (int i = 0; i < 4; ++i) {
        int gr = base + r0 + i;
        if (gr < N_NODES) {
            float di = dinv[gr];
            float4 o = {acc[i].x * di, acc[i].y * di, acc[i].z * di, acc[i].w * di};
            xws4[(size_t)gr * 16 + tx] = o;
        }
    }
}

// One wave per node c, 4 edges in flight (eslot = lane>>4), float4 per lane.
// out[c][:] = b + dinv[c] * (xws[c][:] + sum_e xws[srow[e]][:])
__global__ __launch_bounds__(256) void k_gather(const int* __restrict__ start,
                                                const int* __restrict__ srow,
                                                const float* __restrict__ dinv,
                                                const float4* __restrict__ b4,
                                                const float4* __restrict__ xws4,
                                                float4* __restrict__ out4) {
    int gid = blockIdx.x * 256 + threadIdx.x;
    int c = gid >> 6;
    if (c >= N_NODES) return;
    int lane = threadIdx.x & 63;
    int eslot = lane >> 4;     // which of 4 concurrent edges
    int cg = lane & 15;        // column group (4 floats)

    int s = start[c], e = start[c + 1];
    float4 acc = {0, 0, 0, 0};
    if (eslot == 0) acc = xws4[c * 16 + cg];   // self-loop message (dinv[c]*xw[c])

    for (int base = s; base < e; base += 4) {
        int i = base + eslot;
        if (i < e) {
            int r = srow[i];                    // 16-lane broadcast read
            float4 v = xws4[r * 16 + cg];       // 4 independent 256B rows in flight
            acc.x += v.x; acc.y += v.y; acc.z += v.z; acc.w += v.w;
        }
    }
    // reduce the 4 edge slots (lanes l, l^16, l^32, l^48)
    acc.x += __shfl_xor(acc.x, 16, 64);
    acc.y += __shfl_xor(acc.y, 16, 64);
    acc.z += __shfl_xor(acc.z, 16, 64);
    acc.w += __shfl_xor(acc.w, 16, 64);
    acc.x += __shfl_xor(acc.x, 32, 64);
    acc.y += __shfl_xor(acc.y, 32, 64);
    acc.z += __shfl_xor(acc.z, 32, 64);
    acc.w += __shfl_xor(acc.w, 32, 64);

    if (eslot == 0) {
        float di = dinv[c];
        float4 bb = b4[cg];
        float4 o = {bb.x + di * acc.x, bb.y + di * acc.y,
                    bb.z + di * acc.z, bb.w + di * acc.w};
        out4[c * 16 + cg] = o;
    }
}

extern "C" void kernel_launch(void* const* d_in, const int* in_sizes, int n_in,
                              void* d_out, int out_size, void* d_ws, size_t ws_size,
                              hipStream_t stream) {
    const float* x  = (const float*)d_in[0];
    const int*   ei = (const int*)d_in[1];     // [2, E] int32
    const float* W  = (const float*)d_in[2];
    const float* b  = (const float*)d_in[3];

    const int* row = ei;
    const int* col = ei + N_EDGES;

    // workspace layout, every region 256B-aligned (float4 access to xws)
    char* ws = (char*)d_ws;
    size_t off = 0;
    auto alloc = [&](size_t bytes) {
        char* p = ws + off;
        off = (off + bytes + 255) & ~(size_t)255;
        return p;
    };
    int*   cnt    = (int*)  alloc((size_t)N_NODES * 4);
    float* dinv   = (float*)alloc((size_t)N_NODES * 4);
    int*   start  = (int*)  alloc((size_t)(N_NODES + 1) * 4);
    int*   cursor = (int*)  alloc((size_t)N_NODES * 4);
    int*   bsum   = (int*)  alloc((size_t)NB * 4);
    int*   srow   = (int*)  alloc((size_t)N_EDGES * 4);
    float* xws    = (float*)alloc((size_t)N_NODES * D * 4);
    (void)ws_size;

    hipMemsetAsync(cnt, 0, (size_t)N_NODES * 4, stream);
    k_count <<<(N_EDGES + 255) / 256, 256, 0, stream>>>(col, cnt);
    k_scan1 <<<NB, SCAN_B, 0, stream>>>(cnt, start, bsum);
    k_scan2 <<<1, 128, 0, stream>>>(bsum);
    k_scan3 <<<NB, SCAN_B, 0, stream>>>(start, cursor, bsum, cnt, dinv);
    k_xw    <<<(N_NODES + XW_ROWS - 1) / XW_ROWS, 256, 0, stream>>>(
                (const float4*)x, (const float4*)W, dinv, (float4*)xws);
    k_bucket<<<(N_EDGES + 255) / 256, 256, 0, stream>>>(row, col, cursor, srow);

    long long gt = (long long)N_NODES * D;
    k_gather<<<(int)((gt + 255) / 256), 256, 0, stream>>>(
                start, srow, dinv, (const float4*)b, (const float4*)xws, (float4*)d_out);
}